// Round 2
// baseline (146.478 us; speedup 1.0000x reference)
//
#include <hip/hip_runtime.h>

#define N_NODES 10000
#define N_EDGES 320000
#define DIN 256
#define DOUT 256

// ---------------- zero init (deg + cursor: 20000 ints) ----------------
__global__ void zero_kernel(int* __restrict__ p, int n) {
    int i = blockIdx.x * blockDim.x + threadIdx.x;
    if (i < n) p[i] = 0;
}

// ---------------- degree count ----------------
__global__ void count_deg_kernel(const int* __restrict__ src, int* __restrict__ deg) {
    int e = blockIdx.x * blockDim.x + threadIdx.x;
    if (e < N_EDGES) atomicAdd(&deg[src[e]], 1);
}

// ------------- exclusive prefix scan + d_inv (single block, 256 threads) -------------
__global__ void scan_dinv_kernel(const int* __restrict__ deg, int* __restrict__ rowptr,
                                 float* __restrict__ d_inv) {
    const int T = 256;
    const int per = (N_NODES + T - 1) / T;  // 40
    int tid = threadIdx.x;
    int start = tid * per;
    int sum = 0;
    for (int k = 0; k < per; ++k) {
        int idx = start + k;
        sum += (idx < N_NODES) ? deg[idx] : 0;
    }
    int lane = tid & 63;
    int wid = tid >> 6;
    int x = sum;
    for (int off = 1; off < 64; off <<= 1) {
        int y = __shfl_up(x, off, 64);
        if (lane >= off) x += y;
    }
    __shared__ int wsum[4];
    __shared__ int wbase[4];
    if (lane == 63) wsum[wid] = x;
    __syncthreads();
    if (tid == 0) {
        int acc = 0;
        for (int w = 0; w < 4; ++w) { wbase[w] = acc; acc += wsum[w]; }
    }
    __syncthreads();
    int excl = x - sum + wbase[wid];
    int run = excl;
    for (int k = 0; k < per; ++k) {
        int idx = start + k;
        if (idx < N_NODES) {
            int d = deg[idx];
            rowptr[idx] = run;
            run += d;
            d_inv[idx] = rsqrtf((float)d);
        }
    }
    if (tid == T - 1) rowptr[N_NODES] = run;  // == N_EDGES
}

// ---------------- CSR fill ----------------
__global__ void fill_csr_kernel(const int* __restrict__ src, const int* __restrict__ dst,
                                const int* __restrict__ rowptr, int* __restrict__ cursor,
                                int* __restrict__ col) {
    int e = blockIdx.x * blockDim.x + threadIdx.x;
    if (e < N_EDGES) {
        int s = src[e];
        int p = atomicAdd(&cursor[s], 1);
        col[rowptr[s] + p] = dst[e];
    }
}

// ------- aggregation: wave per node, float4 per lane (64 lanes x 16B = 1KB row) -------
// agg[i] = d_inv[i] * ( sum_{j in N(i)} d_inv[j]*x[j]  +  d_inv[i]*x[i] )
__global__ __launch_bounds__(256) void aggregate_kernel(
    const float4* __restrict__ x4, const float* __restrict__ d_inv,
    const int* __restrict__ rowptr, const int* __restrict__ col,
    float4* __restrict__ agg4) {
    int node = blockIdx.x * 4 + (threadIdx.x >> 6);
    int lane = threadIdx.x & 63;
    if (node >= N_NODES) return;

    float di = d_inv[node];
    float4 xv = x4[node * 64 + lane];
    float ax = di * xv.x, ay = di * xv.y, az = di * xv.z, aw = di * xv.w;

    int beg = rowptr[node], end = rowptr[node + 1];
    for (int k0 = beg; k0 < end; k0 += 64) {
        int kk = k0 + lane;
        int j = 0;
        float dv = 0.0f;
        if (kk < end) {
            j = col[kk];
            dv = d_inv[j];
        }
        int cnt = min(64, end - k0);
        for (int t = 0; t < cnt; ++t) {
            int jt = __shfl(j, t, 64);
            float dvt = __shfl(dv, t, 64);
            float4 xr = x4[jt * 64 + lane];
            ax += dvt * xr.x;
            ay += dvt * xr.y;
            az += dvt * xr.z;
            aw += dvt * xr.w;
        }
    }
    agg4[node * 64 + lane] = make_float4(di * ax, di * ay, di * az, di * aw);
}

// ---------------- GEMM 64x64 tile + bias + relu: out = relu(agg @ W + b) ----------------
__global__ __launch_bounds__(256) void gemm_bias_relu_kernel(
    const float* __restrict__ A, const float* __restrict__ W,
    const float* __restrict__ bias, float* __restrict__ out) {
    __shared__ float a_lds[16][64];  // [k][row]
    __shared__ float b_lds[16][64];  // [k][col]
    const int tid = threadIdx.x;
    const int tx = tid & 15, ty = tid >> 4;
    const int col0 = blockIdx.x * 64;
    const int row0 = blockIdx.y * 64;

    const int ar = tid >> 2;          // 0..63: A row within tile
    const int ak = (tid & 3) * 4;     // 0,4,8,12: A k offset
    const int bk = tid >> 4;          // 0..15: B k
    const int bc = (tid & 15) * 4;    // B col offset

    float acc[4][4] = {};

    for (int k0 = 0; k0 < DIN; k0 += 16) {
        int arow = row0 + ar;
        float4 av4 = make_float4(0.f, 0.f, 0.f, 0.f);
        if (arow < N_NODES) av4 = *(const float4*)&A[arow * DIN + k0 + ak];
        float4 bv4 = *(const float4*)&W[(k0 + bk) * DOUT + col0 + bc];
        __syncthreads();
        a_lds[ak + 0][ar] = av4.x;
        a_lds[ak + 1][ar] = av4.y;
        a_lds[ak + 2][ar] = av4.z;
        a_lds[ak + 3][ar] = av4.w;
        *(float4*)&b_lds[bk][bc] = bv4;
        __syncthreads();
#pragma unroll
        for (int k = 0; k < 16; ++k) {
            float4 av = *(const float4*)&a_lds[k][ty * 4];
            float4 bv = *(const float4*)&b_lds[k][tx * 4];
            float a[4] = {av.x, av.y, av.z, av.w};
            float b4[4] = {bv.x, bv.y, bv.z, bv.w};
#pragma unroll
            for (int r = 0; r < 4; ++r)
#pragma unroll
                for (int c = 0; c < 4; ++c)
                    acc[r][c] += a[r] * b4[c];
        }
    }

#pragma unroll
    for (int r = 0; r < 4; ++r) {
        int row = row0 + ty * 4 + r;
        if (row < N_NODES) {
            float4 v;
            v.x = fmaxf(acc[r][0] + bias[col0 + tx * 4 + 0], 0.f);
            v.y = fmaxf(acc[r][1] + bias[col0 + tx * 4 + 1], 0.f);
            v.z = fmaxf(acc[r][2] + bias[col0 + tx * 4 + 2], 0.f);
            v.w = fmaxf(acc[r][3] + bias[col0 + tx * 4 + 3], 0.f);
            *(float4*)&out[row * DOUT + col0 + tx * 4] = v;
        }
    }
}

extern "C" void kernel_launch(void* const* d_in, const int* in_sizes, int n_in,
                              void* d_out, int out_size, void* d_ws, size_t ws_size,
                              hipStream_t stream) {
    const float* x = (const float*)d_in[0];
    const int* edge_index = (const int*)d_in[1];
    const float* W = (const float*)d_in[2];
    const float* b = (const float*)d_in[3];
    float* out = (float*)d_out;

    const int* src = edge_index;            // edge_index[0, :]
    const int* dst = edge_index + N_EDGES;  // edge_index[1, :]

    char* ws = (char*)d_ws;
    int* deg    = (int*)(ws + 0);          // 40000 B
    int* cursor = (int*)(ws + 40000);      // 40000 B  (deg+cursor zeroed together)
    int* rowptr = (int*)(ws + 80000);      // 40004 B
    float* dinv = (float*)(ws + 120320);   // 40000 B
    int* col    = (int*)(ws + 160512);     // 1280000 B
    float* agg  = (float*)(ws + 1440768);  // 10240000 B; total ~11.7 MB

    zero_kernel<<<(20000 + 255) / 256, 256, 0, stream>>>(deg, 20000);  // deg + cursor
    count_deg_kernel<<<(N_EDGES + 255) / 256, 256, 0, stream>>>(src, deg);
    scan_dinv_kernel<<<1, 256, 0, stream>>>(deg, rowptr, dinv);
    fill_csr_kernel<<<(N_EDGES + 255) / 256, 256, 0, stream>>>(src, dst, rowptr, cursor, col);
    aggregate_kernel<<<(N_NODES + 3) / 4, 256, 0, stream>>>(
        (const float4*)x, dinv, rowptr, col, (float4*)agg);
    gemm_bias_relu_kernel<<<dim3(DOUT / 64, (N_NODES + 63) / 64), 256, 0, stream>>>(agg, W, b, out);
}

// Round 3
// 131.376 us; speedup vs baseline: 1.1150x; 1.1150x over previous
//
#include <hip/hip_runtime.h>

#define N_NODES 10000
#define N_EDGES 320000
#define DIN 256
#define DOUT 256
#define M_PAD 10048  // 157 * 64

typedef short bf16x8 __attribute__((ext_vector_type(8)));
typedef float f32x4 __attribute__((ext_vector_type(4)));

__device__ __forceinline__ unsigned bfrne(float f) {  // f32 -> bf16 bits (RNE)
    unsigned u = __float_as_uint(f);
    return (u + 0x7fffu + ((u >> 16) & 1u)) >> 16;
}

// ---------------- zero deg ----------------
__global__ void zero_kernel(int* __restrict__ p, int n) {
    int i = blockIdx.x * blockDim.x + threadIdx.x;
    if (i < n) p[i] = 0;
}

// ---------------- degree count ----------------
__global__ void count_deg_kernel(const int* __restrict__ src, int* __restrict__ deg) {
    int e = blockIdx.x * blockDim.x + threadIdx.x;
    if (e < N_EDGES) atomicAdd(&deg[src[e]], 1);
}

// ------------- exclusive prefix scan + d_inv (single block, 256 threads) -------------
__global__ void scan_dinv_kernel(const int* __restrict__ deg, int* __restrict__ rowptr,
                                 float* __restrict__ d_inv) {
    const int T = 256;
    const int per = (N_NODES + T - 1) / T;  // 40
    int tid = threadIdx.x;
    int start = tid * per;
    int sum = 0;
    for (int k = 0; k < per; ++k) {
        int idx = start + k;
        sum += (idx < N_NODES) ? deg[idx] : 0;
    }
    int lane = tid & 63;
    int wid = tid >> 6;
    int x = sum;
    for (int off = 1; off < 64; off <<= 1) {
        int y = __shfl_up(x, off, 64);
        if (lane >= off) x += y;
    }
    __shared__ int wsum[4];
    __shared__ int wbase[4];
    if (lane == 63) wsum[wid] = x;
    __syncthreads();
    if (tid == 0) {
        int acc = 0;
        for (int w = 0; w < 4; ++w) { wbase[w] = acc; acc += wsum[w]; }
    }
    __syncthreads();
    int excl = x - sum + wbase[wid];
    int run = excl;
    for (int k = 0; k < per; ++k) {
        int idx = start + k;
        if (idx < N_NODES) {
            int d = deg[idx];
            rowptr[idx] = run;
            run += d;
            d_inv[idx] = rsqrtf((float)d);
        }
    }
    if (tid == T - 1) rowptr[N_NODES] = run;  // == N_EDGES
}

// ---------------- CSR fill (consumes deg as cursor via atomicSub) ----------------
__global__ void fill_csr_kernel(const int* __restrict__ src, const int* __restrict__ dst,
                                const int* __restrict__ rowptr, int* __restrict__ deg,
                                int* __restrict__ col) {
    int e = blockIdx.x * blockDim.x + threadIdx.x;
    if (e < N_EDGES) {
        int s = src[e];
        int p = atomicSub(&deg[s], 1) - 1;
        col[rowptr[s] + p] = dst[e];
    }
}

// ------- prep: xs[i] = bf16(d_inv[i] * x[i])  and  Wt[col][k] = bf16(W[k][col]) -------
#define NX4 (N_NODES * 64)  // 640000 float4-groups of x
#define NW4 (DIN * 64)      // 16384 float4-groups of W
__global__ __launch_bounds__(256) void prep_kernel(
    const float4* __restrict__ x4, const float4* __restrict__ W4,
    const float* __restrict__ d_inv, uint2* __restrict__ xs4, ushort* __restrict__ Wt) {
    int g = blockIdx.x * blockDim.x + threadIdx.x;
    if (g < NX4) {
        int i = g >> 6;
        float di = d_inv[i];
        float4 v = x4[g];
        uint2 o;
        o.x = bfrne(di * v.x) | (bfrne(di * v.y) << 16);
        o.y = bfrne(di * v.z) | (bfrne(di * v.w) << 16);
        xs4[g] = o;
    } else if (g - NX4 < NW4) {
        int g2 = g - NX4;
        int k = g2 >> 6;
        int c0 = (g2 & 63) * 4;
        float4 w = W4[g2];  // W[k][c0..c0+3], coalesced read
        Wt[(c0 + 0) * DIN + k] = (ushort)bfrne(w.x);
        Wt[(c0 + 1) * DIN + k] = (ushort)bfrne(w.y);
        Wt[(c0 + 2) * DIN + k] = (ushort)bfrne(w.z);
        Wt[(c0 + 3) * DIN + k] = (ushort)bfrne(w.w);
    }
}

// ------- aggregation (bf16 gather): aggb[i] = bf16( d_inv[i] * (xs[i] + sum_j xs[j]) ) -------
// wave per node; lane covers 4 channels (uint2 = 4 bf16); 64 lanes * 8B = 512B row.
__global__ __launch_bounds__(256) void aggregate_kernel(
    const uint2* __restrict__ xs4, const float* __restrict__ d_inv,
    const int* __restrict__ rowptr, const int* __restrict__ col,
    uint2* __restrict__ aggb4) {
    int node = blockIdx.x * 4 + (threadIdx.x >> 6);
    int lane = threadIdx.x & 63;
    if (node >= N_NODES) return;

    uint2 sv = xs4[node * 64 + lane];  // self term (xs already has d_inv[i]*x[i])
    float a0 = __uint_as_float(sv.x << 16);
    float a1 = __uint_as_float(sv.x & 0xffff0000u);
    float a2 = __uint_as_float(sv.y << 16);
    float a3 = __uint_as_float(sv.y & 0xffff0000u);

    int beg = rowptr[node], end = rowptr[node + 1];
    for (int k0 = beg; k0 < end; k0 += 64) {
        int kk = k0 + lane;
        int j = (kk < end) ? col[kk] : 0;
        int cnt = min(64, end - k0);
        for (int t = 0; t < cnt; ++t) {
            int jt = __shfl(j, t, 64);
            uint2 xv = xs4[jt * 64 + lane];
            a0 += __uint_as_float(xv.x << 16);
            a1 += __uint_as_float(xv.x & 0xffff0000u);
            a2 += __uint_as_float(xv.y << 16);
            a3 += __uint_as_float(xv.y & 0xffff0000u);
        }
    }
    float di = d_inv[node];
    uint2 o;
    o.x = bfrne(di * a0) | (bfrne(di * a1) << 16);
    o.y = bfrne(di * a2) | (bfrne(di * a3) << 16);
    aggb4[node * 64 + lane] = o;
}

// ---------------- MFMA GEMM: out = relu(aggb @ W + b), bf16 inputs, f32 out ----------------
// wave computes one 16x16 tile; block = 4 waves = 64 rows x 16 cols.
// A frag: lane holds aggb[row0+(lane&15)][k0 + (lane>>4)*8 .. +8)  (16B contiguous)
// B frag: lane holds Wt[col0+(lane&15)][k0 + (lane>>4)*8 .. +8)    (16B contiguous)
// C/D:    col = lane&15, row = (lane>>4)*4 + reg   [verified layout]
__global__ __launch_bounds__(256) void gemm_mfma_kernel(
    const ushort* __restrict__ aggb, const ushort* __restrict__ Wt,
    const float* __restrict__ bias, float* __restrict__ out) {
    int wid = threadIdx.x >> 6;
    int lane = threadIdx.x & 63;
    int row0 = blockIdx.y * 64 + wid * 16;
    int col0 = blockIdx.x * 16;
    int r = lane & 15;
    int ko = (lane >> 4) * 8;

    const ushort* ap = aggb + (row0 + r) * DIN + ko;
    const ushort* bp = Wt + (col0 + r) * DIN + ko;

    f32x4 acc = {0.f, 0.f, 0.f, 0.f};
#pragma unroll
    for (int k = 0; k < DIN; k += 32) {
        bf16x8 a = *(const bf16x8*)(ap + k);
        bf16x8 b = *(const bf16x8*)(bp + k);
        acc = __builtin_amdgcn_mfma_f32_16x16x32_bf16(a, b, acc, 0, 0, 0);
    }

    int ocol = col0 + r;
    float bv = bias[ocol];
    int rbase = row0 + (lane >> 4) * 4;
#pragma unroll
    for (int i = 0; i < 4; ++i) {
        int orow = rbase + i;
        if (orow < N_NODES) out[orow * DOUT + ocol] = fmaxf(acc[i] + bv, 0.f);
    }
}

extern "C" void kernel_launch(void* const* d_in, const int* in_sizes, int n_in,
                              void* d_out, int out_size, void* d_ws, size_t ws_size,
                              hipStream_t stream) {
    const float* x = (const float*)d_in[0];
    const int* edge_index = (const int*)d_in[1];
    const float* W = (const float*)d_in[2];
    const float* b = (const float*)d_in[3];
    float* out = (float*)d_out;

    const int* src = edge_index;            // edge_index[0, :]
    const int* dst = edge_index + N_EDGES;  // edge_index[1, :]

    char* ws = (char*)d_ws;
    int* deg      = (int*)(ws + 0);         // 40000
    int* rowptr   = (int*)(ws + 40064);     // 40004
    float* dinv   = (float*)(ws + 80128);   // 40000
    int* col      = (int*)(ws + 120192);    // 1280000
    ushort* xs    = (ushort*)(ws + 1400320); // 5120000 (bf16 10000x256)
    ushort* Wt    = (ushort*)(ws + 6520320); // 131072  (bf16 256x256, transposed)
    ushort* aggb  = (ushort*)(ws + 6651392); // 5144576 (bf16 10048x256) -> total ~11.8MB

    zero_kernel<<<(N_NODES + 255) / 256, 256, 0, stream>>>(deg, N_NODES);
    count_deg_kernel<<<(N_EDGES + 255) / 256, 256, 0, stream>>>(src, deg);
    scan_dinv_kernel<<<1, 256, 0, stream>>>(deg, rowptr, dinv);
    fill_csr_kernel<<<(N_EDGES + 255) / 256, 256, 0, stream>>>(src, dst, rowptr, deg, col);
    prep_kernel<<<(NX4 + NW4 + 255) / 256, 256, 0, stream>>>(
        (const float4*)x, (const float4*)W, dinv, (uint2*)xs, Wt);
    aggregate_kernel<<<(N_NODES + 3) / 4, 256, 0, stream>>>(
        (const uint2*)xs, dinv, rowptr, col, (uint2*)aggb);
    gemm_mfma_kernel<<<dim3(DOUT / 16, M_PAD / 64), 256, 0, stream>>>(aggb, Wt, b, out);
}